// Round 1
// baseline (1067.811 us; speedup 1.0000x reference)
//
#include <hip/hip_runtime.h>
#include <hip/hip_bf16.h>
#include <stdint.h>

using bf16 = __hip_bfloat16;
typedef __attribute__((ext_vector_type(8))) short bf16x8;
typedef __attribute__((ext_vector_type(4))) float f32x4;

#define SCALE 0.125f

__device__ __forceinline__ float b2f(bf16 x) { return __bfloat162float(x); }
__device__ __forceinline__ bf16 f2b(float x) { return __float2bfloat16(x); }

// ---------------- fp32 -> bf16 conversion ----------------
__global__ __launch_bounds__(256) void cvt_kernel(const float* __restrict__ in, bf16* __restrict__ out, int n4) {
  int i = blockIdx.x * 256 + threadIdx.x;
  if (i >= n4) return;
  float4 v = ((const float4*)in)[i];
  alignas(8) bf16 o[4];
  o[0] = f2b(v.x); o[1] = f2b(v.y); o[2] = f2b(v.z); o[3] = f2b(v.w);
  ((uint2*)out)[i] = *(const uint2*)o;
}

// ---------------- GEMM: C[m,n] = sum_k A[m,k] * B[n,k]  (A:[M,K], B:[N,K] row-major bf16)
template<int STORE_BF16>
__global__ __launch_bounds__(256) void gemm_bt(const bf16* __restrict__ A, const bf16* __restrict__ B,
                                               void* __restrict__ C, int M, int N, int K) {
  __shared__ bf16 As[128][72];
  __shared__ bf16 Bs[128][72];
  const int tid = threadIdx.x;
  const int lane = tid & 63;
  const int w = tid >> 6, wr = w >> 1, wc = w & 1;
  const int m0 = blockIdx.y * 128, n0 = blockIdx.x * 128;
  const int lr = lane & 15, lg = lane >> 4;
  f32x4 acc[4][4] = {};
  for (int k0 = 0; k0 < K; k0 += 64) {
    __syncthreads();
#pragma unroll
    for (int i = 0; i < 4; ++i) {
      int c = tid + i * 256;           // 0..1023 chunks of 8 bf16
      int row = c >> 3, seg = c & 7;
      *(int4*)&As[row][seg * 8] = *(const int4*)&A[(size_t)(m0 + row) * K + k0 + seg * 8];
      *(int4*)&Bs[row][seg * 8] = *(const int4*)&B[(size_t)(n0 + row) * K + k0 + seg * 8];
    }
    __syncthreads();
#pragma unroll
    for (int kk = 0; kk < 2; ++kk) {
      bf16x8 af[4], bfv[4];
#pragma unroll
      for (int m = 0; m < 4; ++m) af[m] = *(const bf16x8*)&As[wr * 64 + m * 16 + lr][kk * 32 + lg * 8];
#pragma unroll
      for (int n = 0; n < 4; ++n) bfv[n] = *(const bf16x8*)&Bs[wc * 64 + n * 16 + lr][kk * 32 + lg * 8];
#pragma unroll
      for (int m = 0; m < 4; ++m)
#pragma unroll
        for (int n = 0; n < 4; ++n)
          acc[m][n] = __builtin_amdgcn_mfma_f32_16x16x32_bf16(af[m], bfv[n], acc[m][n], 0, 0, 0);
    }
  }
#pragma unroll
  for (int m = 0; m < 4; ++m)
#pragma unroll
    for (int n = 0; n < 4; ++n)
#pragma unroll
      for (int r = 0; r < 4; ++r) {
        int row = m0 + wr * 64 + m * 16 + lg * 4 + r;
        int col = n0 + wc * 64 + n * 16 + lr;
        if (STORE_BF16) ((bf16*)C)[(size_t)row * N + col] = f2b(acc[m][n][r]);
        else            ((float*)C)[(size_t)row * N + col] = acc[m][n][r];
      }
}

// ---------------- BD = ((q + r_r_bias)*SCALE) @ rk^T with rel_shift scatter epilogue
// P[m,c] -> (i=m, j=m+c-2047) if c >= 2047-m else (i=m-1, j=m+c+1); row i=-1 dropped.
__global__ __launch_bounds__(256) void bd_kernel(const bf16* __restrict__ wh, const bf16* __restrict__ rk,
                                                 const float* __restrict__ rrb, bf16* __restrict__ bds, int bn0) {
  const int z = blockIdx.z, bn = bn0 + z;
  const int b = bn >> 4, n = bn & 15;
  const int m0 = blockIdx.y * 128, c0 = blockIdx.x * 128;
  __shared__ bf16 As[128][72];
  __shared__ bf16 Bs[128][72];
  const int tid = threadIdx.x, lane = tid & 63;
  const int w = tid >> 6, wr = w >> 1, wc = w & 1;
  const int lr = lane & 15, lg = lane >> 4;
#pragma unroll
  for (int i = 0; i < 4; ++i) {
    int c = tid + i * 256;
    int row = c >> 3, seg = c & 7;
    int4 raw = *(const int4*)&wh[((size_t)(m0 + row) * 4 + b) * 3072 + n * 64 + seg * 8];
    const bf16* rp = (const bf16*)&raw;
    alignas(16) bf16 ov[8];
#pragma unroll
    for (int e = 0; e < 8; ++e) ov[e] = f2b((b2f(rp[e]) + rrb[n * 64 + seg * 8 + e]) * SCALE);
    *(int4*)&As[row][seg * 8] = *(const int4*)ov;
    *(int4*)&Bs[row][seg * 8] = *(const int4*)&rk[(size_t)(c0 + row) * 1024 + n * 64 + seg * 8];
  }
  __syncthreads();
  f32x4 acc[4][4] = {};
#pragma unroll
  for (int kk = 0; kk < 2; ++kk) {
    bf16x8 af[4], bfv[4];
#pragma unroll
    for (int m = 0; m < 4; ++m) af[m] = *(const bf16x8*)&As[wr * 64 + m * 16 + lr][kk * 32 + lg * 8];
#pragma unroll
    for (int nn = 0; nn < 4; ++nn) bfv[nn] = *(const bf16x8*)&Bs[wc * 64 + nn * 16 + lr][kk * 32 + lg * 8];
#pragma unroll
    for (int m = 0; m < 4; ++m)
#pragma unroll
      for (int nn = 0; nn < 4; ++nn)
        acc[m][nn] = __builtin_amdgcn_mfma_f32_16x16x32_bf16(af[m], bfv[nn], acc[m][nn], 0, 0, 0);
  }
  const size_t base = (size_t)z * 2048 * 2048;
#pragma unroll
  for (int m = 0; m < 4; ++m)
#pragma unroll
    for (int nn = 0; nn < 4; ++nn)
#pragma unroll
      for (int r = 0; r < 4; ++r) {
        int mm = m0 + wr * 64 + m * 16 + lg * 4 + r;
        int cc = c0 + wc * 64 + nn * 16 + lr;
        int i, j;
        if (cc >= 2047 - mm) { i = mm;     j = mm + cc - 2047; }
        else                 { i = mm - 1; j = mm + cc + 1; }
        if (i >= 0) bds[base + (size_t)i * 2048 + j] = f2b(acc[m][nn][r]);
      }
}

// ---------------- flash attention per (b,n,q-tile): S = (Q+rwb)*SCALE @ K^T + BDshift, online softmax, O = P@V
__global__ __launch_bounds__(256) void flash_kernel(const bf16* __restrict__ wh, const float* __restrict__ rwb,
                                                    const bf16* __restrict__ bds, bf16* __restrict__ av, int bn0) {
  const int z = blockIdx.y, bn = bn0 + z;
  const int b = bn >> 4, n = bn & 15;
  const int q0 = blockIdx.x * 64;
  const int tid = threadIdx.x, lane = tid & 63, w = tid >> 6;
  const int lr = lane & 15, lg = lane >> 4;
  __shared__ bf16 Qs[64][72];
  __shared__ bf16 Ks[64][72];
  __shared__ bf16 Vt[64][72];
  __shared__ bf16 Ps[64][72];
#pragma unroll
  for (int i = 0; i < 2; ++i) {
    int c = tid + i * 256;
    int row = c >> 3, seg = c & 7;
    int4 raw = *(const int4*)&wh[((size_t)(q0 + row) * 4 + b) * 3072 + n * 64 + seg * 8];
    const bf16* rp = (const bf16*)&raw;
    alignas(16) bf16 ov[8];
#pragma unroll
    for (int e = 0; e < 8; ++e) ov[e] = f2b((b2f(rp[e]) + rwb[n * 64 + seg * 8 + e]) * SCALE);
    *(int4*)&Qs[row][seg * 8] = *(const int4*)ov;
  }
  __syncthreads();
  bf16x8 qf[2];
  qf[0] = *(const bf16x8*)&Qs[w * 16 + lr][lg * 8];
  qf[1] = *(const bf16x8*)&Qs[w * 16 + lr][32 + lg * 8];
  float mrow[4] = {-1e30f, -1e30f, -1e30f, -1e30f};
  float lrow[4] = {0.f, 0.f, 0.f, 0.f};
  f32x4 oacc[4] = {};
  const size_t bdbase = (size_t)z * 2048 * 2048;
  for (int j0 = 0; j0 < 2048; j0 += 64) {
    __syncthreads();
#pragma unroll
    for (int i = 0; i < 2; ++i) {
      int c = tid + i * 256;
      int row = c >> 3, seg = c & 7;
      *(int4*)&Ks[row][seg * 8] = *(const int4*)&wh[((size_t)(j0 + row) * 4 + b) * 3072 + 1024 + n * 64 + seg * 8];
      int4 vv = *(const int4*)&wh[((size_t)(j0 + row) * 4 + b) * 3072 + 2048 + n * 64 + seg * 8];
      const bf16* vp = (const bf16*)&vv;
#pragma unroll
      for (int e = 0; e < 8; ++e) Vt[seg * 8 + e][row] = vp[e];
    }
    __syncthreads();
    f32x4 s[4] = {};
#pragma unroll
    for (int kk = 0; kk < 2; ++kk)
#pragma unroll
      for (int f = 0; f < 4; ++f) {
        bf16x8 kf = *(const bf16x8*)&Ks[f * 16 + lr][kk * 32 + lg * 8];
        s[f] = __builtin_amdgcn_mfma_f32_16x16x32_bf16(qf[kk], kf, s[f], 0, 0, 0);
      }
    // add shifted BD (pad-zero at j == i+1)
#pragma unroll
    for (int f = 0; f < 4; ++f)
#pragma unroll
      for (int r = 0; r < 4; ++r) {
        int i = q0 + w * 16 + lg * 4 + r;
        int j = j0 + f * 16 + lr;
        float bd = (j == i + 1) ? 0.f : b2f(bds[bdbase + (size_t)i * 2048 + j]);
        s[f][r] += bd;
      }
    // online softmax (rows live in 16-lane groups: reduce over xor 1,2,4,8)
    float al[4];
#pragma unroll
    for (int r = 0; r < 4; ++r) {
      float mx = fmaxf(fmaxf(s[0][r], s[1][r]), fmaxf(s[2][r], s[3][r]));
#pragma unroll
      for (int msk = 1; msk <= 8; msk <<= 1) mx = fmaxf(mx, __shfl_xor(mx, msk));
      float mnew = fmaxf(mrow[r], mx);
      al[r] = __expf(mrow[r] - mnew);
      float rs = 0.f;
#pragma unroll
      for (int f = 0; f < 4; ++f) { float p = __expf(s[f][r] - mnew); s[f][r] = p; rs += p; }
#pragma unroll
      for (int msk = 1; msk <= 8; msk <<= 1) rs += __shfl_xor(rs, msk);
      lrow[r] = lrow[r] * al[r] + rs;
      mrow[r] = mnew;
    }
#pragma unroll
    for (int f = 0; f < 4; ++f)
#pragma unroll
      for (int r = 0; r < 4; ++r) Ps[w * 16 + lg * 4 + r][f * 16 + lr] = f2b(s[f][r]);
#pragma unroll
    for (int df = 0; df < 4; ++df) {
      oacc[df][0] *= al[0]; oacc[df][1] *= al[1]; oacc[df][2] *= al[2]; oacc[df][3] *= al[3];
    }
#pragma unroll
    for (int kk = 0; kk < 2; ++kk) {
      bf16x8 pf = *(const bf16x8*)&Ps[w * 16 + lr][kk * 32 + lg * 8];
#pragma unroll
      for (int df = 0; df < 4; ++df) {
        bf16x8 vf = *(const bf16x8*)&Vt[df * 16 + lr][kk * 32 + lg * 8];
        oacc[df] = __builtin_amdgcn_mfma_f32_16x16x32_bf16(pf, vf, oacc[df], 0, 0, 0);
      }
    }
  }
#pragma unroll
  for (int df = 0; df < 4; ++df)
#pragma unroll
    for (int r = 0; r < 4; ++r) {
      int i = q0 + w * 16 + lg * 4 + r;
      av[((size_t)i * 4 + b) * 1024 + n * 64 + df * 16 + lr] = f2b(oacc[df][r] / lrow[r]);
    }
}

// ---------------- residual + LayerNorm ----------------
__global__ __launch_bounds__(256) void ln_kernel(const float* __restrict__ w, const float* __restrict__ ao,
                                                 const float* __restrict__ g, const float* __restrict__ bb,
                                                 float* __restrict__ out) {
  const int row = blockIdx.x;
  const int t = threadIdx.x;
  const float4 wv = ((const float4*)(w + (size_t)row * 1024))[t];
  const float4 av = ((const float4*)(ao + (size_t)row * 1024))[t];
  float x0 = wv.x + av.x, x1 = wv.y + av.y, x2 = wv.z + av.z, x3 = wv.w + av.w;
  float s1 = x0 + x1 + x2 + x3;
  float s2 = x0 * x0 + x1 * x1 + x2 * x2 + x3 * x3;
#pragma unroll
  for (int m = 1; m <= 32; m <<= 1) { s1 += __shfl_xor(s1, m); s2 += __shfl_xor(s2, m); }
  __shared__ float red[8];
  const int lane = t & 63, wv2 = t >> 6;
  if (lane == 0) { red[wv2] = s1; red[4 + wv2] = s2; }
  __syncthreads();
  s1 = red[0] + red[1] + red[2] + red[3];
  s2 = red[4] + red[5] + red[6] + red[7];
  const float mu = s1 * (1.f / 1024.f);
  const float var = s2 * (1.f / 1024.f) - mu * mu;
  const float rr = rsqrtf(var + 1e-5f);
  const float4 gv = ((const float4*)g)[t];
  const float4 bv = ((const float4*)bb)[t];
  float4 o;
  o.x = (x0 - mu) * rr * gv.x + bv.x;
  o.y = (x1 - mu) * rr * gv.y + bv.y;
  o.z = (x2 - mu) * rr * gv.z + bv.z;
  o.w = (x3 - mu) * rr * gv.w + bv.w;
  ((float4*)(out + (size_t)row * 1024))[t] = o;
}

extern "C" void kernel_launch(void* const* d_in, const int* in_sizes, int n_in,
                              void* d_out, int out_size, void* d_ws, size_t ws_size,
                              hipStream_t stream) {
  const float* w    = (const float*)d_in[0];
  const float* r    = (const float*)d_in[1];
  const float* qkvw = (const float*)d_in[2];
  const float* rnw  = (const float*)d_in[3];
  const float* ow   = (const float*)d_in[4];
  const float* rwb  = (const float*)d_in[5];
  const float* rrb  = (const float*)d_in[6];
  const float* lng  = (const float*)d_in[7];
  const float* lnb  = (const float*)d_in[8];
  float* out = (float*)d_out;

  char* ws = (char*)d_ws;
  size_t off = 0;
  auto alloc = [&](size_t bytes) -> char* {
    char* p = ws + off; off += (bytes + 255) & ~((size_t)255); return p;
  };
  bf16*  wb  = (bf16*)alloc((size_t)8192 * 1024 * 2);
  bf16*  qb  = (bf16*)alloc((size_t)3072 * 1024 * 2);
  bf16*  rb  = (bf16*)alloc((size_t)2048 * 1024 * 2);
  bf16*  rnb = (bf16*)alloc((size_t)1024 * 1024 * 2);
  bf16*  owb = (bf16*)alloc((size_t)1024 * 1024 * 2);
  bf16*  wh  = (bf16*)alloc((size_t)8192 * 3072 * 2);
  bf16*  rkb = (bf16*)alloc((size_t)2048 * 1024 * 2);
  bf16*  avb = (bf16*)alloc((size_t)8192 * 1024 * 2);
  float* ao  = (float*)alloc((size_t)8192 * 1024 * 4);
  size_t fixed = off;
  bf16* bds = (bf16*)(ws + fixed);
  size_t bd_bytes = (size_t)2048 * 2048 * 2;
  int g = 1;
  if (ws_size > fixed) {
    size_t avail = (ws_size - fixed) / bd_bytes;
    g = (avail >= 64) ? 64 : (avail < 1 ? 1 : (int)avail);
  }

  auto cvt = [&](const float* in, bf16* o, size_t nelem) {
    int n4 = (int)(nelem / 4);
    cvt_kernel<<<dim3((n4 + 255) / 256), dim3(256), 0, stream>>>(in, o, n4);
  };
  cvt(w, wb, (size_t)8192 * 1024);
  cvt(qkvw, qb, (size_t)3072 * 1024);
  cvt(r, rb, (size_t)2048 * 1024);
  cvt(rnw, rnb, (size_t)1024 * 1024);
  cvt(ow, owb, (size_t)1024 * 1024);

  gemm_bt<1><<<dim3(3072 / 128, 8192 / 128), dim3(256), 0, stream>>>(wb, qb, wh, 8192, 3072, 1024);
  gemm_bt<1><<<dim3(1024 / 128, 2048 / 128), dim3(256), 0, stream>>>(rb, rnb, rkb, 2048, 1024, 1024);

  for (int s0 = 0; s0 < 64; s0 += g) {
    int cnt = (64 - s0) < g ? (64 - s0) : g;
    bd_kernel<<<dim3(16, 16, cnt), dim3(256), 0, stream>>>(wh, rkb, rrb, bds, s0);
    flash_kernel<<<dim3(32, cnt), dim3(256), 0, stream>>>(wh, rwb, bds, avb, s0);
  }

  gemm_bt<0><<<dim3(1024 / 128, 8192 / 128), dim3(256), 0, stream>>>(avb, owb, ao, 8192, 1024, 1024);
  ln_kernel<<<dim3(8192), dim3(256), 0, stream>>>(w, ao, lng, lnb, out);
}

// Round 2
// 686.947 us; speedup vs baseline: 1.5544x; 1.5544x over previous
//
#include <hip/hip_runtime.h>
#include <hip/hip_bf16.h>
#include <stdint.h>

using bf16 = __hip_bfloat16;
typedef __attribute__((ext_vector_type(8))) short bf16x8;
typedef __attribute__((ext_vector_type(4))) float f32x4;

#define SCALE 0.125f

__device__ __forceinline__ float b2f(bf16 x) { return __bfloat162float(x); }
__device__ __forceinline__ bf16 f2b(float x) { return __float2bfloat16(x); }

// ---------------- fp32 -> bf16 conversion ----------------
__global__ __launch_bounds__(256) void cvt_kernel(const float* __restrict__ in, bf16* __restrict__ out, int n4) {
  int i = blockIdx.x * 256 + threadIdx.x;
  if (i >= n4) return;
  float4 v = ((const float4*)in)[i];
  alignas(8) bf16 o[4];
  o[0] = f2b(v.x); o[1] = f2b(v.y); o[2] = f2b(v.z); o[3] = f2b(v.w);
  ((uint2*)out)[i] = *(const uint2*)o;
}

// ---------------- GEMM: C[m,n] = sum_k A[m,k] * B[n,k]  (A:[M,K], B:[N,K] row-major bf16)
template<int STORE_BF16>
__global__ __launch_bounds__(256) void gemm_bt(const bf16* __restrict__ A, const bf16* __restrict__ B,
                                               void* __restrict__ C, int M, int N, int K) {
  __shared__ bf16 As[128][72];
  __shared__ bf16 Bs[128][72];
  const int tid = threadIdx.x;
  const int lane = tid & 63;
  const int w = tid >> 6, wr = w >> 1, wc = w & 1;
  const int m0 = blockIdx.y * 128, n0 = blockIdx.x * 128;
  const int lr = lane & 15, lg = lane >> 4;
  f32x4 acc[4][4] = {};
  for (int k0 = 0; k0 < K; k0 += 64) {
    __syncthreads();
#pragma unroll
    for (int i = 0; i < 4; ++i) {
      int c = tid + i * 256;           // 0..1023 chunks of 8 bf16
      int row = c >> 3, seg = c & 7;
      *(int4*)&As[row][seg * 8] = *(const int4*)&A[(size_t)(m0 + row) * K + k0 + seg * 8];
      *(int4*)&Bs[row][seg * 8] = *(const int4*)&B[(size_t)(n0 + row) * K + k0 + seg * 8];
    }
    __syncthreads();
#pragma unroll
    for (int kk = 0; kk < 2; ++kk) {
      bf16x8 af[4], bfv[4];
#pragma unroll
      for (int m = 0; m < 4; ++m) af[m] = *(const bf16x8*)&As[wr * 64 + m * 16 + lr][kk * 32 + lg * 8];
#pragma unroll
      for (int n = 0; n < 4; ++n) bfv[n] = *(const bf16x8*)&Bs[wc * 64 + n * 16 + lr][kk * 32 + lg * 8];
#pragma unroll
      for (int m = 0; m < 4; ++m)
#pragma unroll
        for (int n = 0; n < 4; ++n)
          acc[m][n] = __builtin_amdgcn_mfma_f32_16x16x32_bf16(af[m], bfv[n], acc[m][n], 0, 0, 0);
    }
  }
#pragma unroll
  for (int m = 0; m < 4; ++m)
#pragma unroll
    for (int n = 0; n < 4; ++n)
#pragma unroll
      for (int r = 0; r < 4; ++r) {
        int row = m0 + wr * 64 + m * 16 + lg * 4 + r;
        int col = n0 + wc * 64 + n * 16 + lr;
        if (STORE_BF16) ((bf16*)C)[(size_t)row * N + col] = f2b(acc[m][n][r]);
        else            ((float*)C)[(size_t)row * N + col] = acc[m][n][r];
      }
}

// ---------------- fused flash attention with in-kernel rel-shift BD
// For rows i in [q0,q0+64), cols j: u = j-i
//   u<=0 : BD = qr_i     . rk[u+2047]
//   u==1 : BD = 0
//   u>=2 : BD = qr_{i+1} . rk[u-2]
// Rolling 128-col bf16 panel Tp (coordinate mod 128); one 64-col panel GEMM per j-block.
__global__ __launch_bounds__(256) void flash_kernel(const bf16* __restrict__ wh, const bf16* __restrict__ rk,
                                                    const float* __restrict__ rwb, const float* __restrict__ rrb,
                                                    bf16* __restrict__ av) {
  const int bn = blockIdx.y;
  const int b = bn >> 4, n = bn & 15;
  const int q0 = blockIdx.x * 64;
  const int tid = threadIdx.x, lane = tid & 63, w = tid >> 6;
  const int lr = lane & 15, lg = lane >> 4;
  __shared__ bf16 Ks[64][72];
  __shared__ bf16 Vt[64][72];
  __shared__ bf16 Ps[64][72];
  __shared__ bf16 Tp[64][128];

  // --- load Q fragments (AC path, +r_w_bias) and Qr fragments (BD path, +r_r_bias, rows +0/+1)
  bf16x8 qf[2], qrf[2][2];
#pragma unroll
  for (int kk = 0; kk < 2; ++kk) {
    {
      int row = q0 + w * 16 + lr;
      int4 raw = *(const int4*)&wh[((size_t)row * 4 + b) * 3072 + n * 64 + kk * 32 + lg * 8];
      const bf16* rp = (const bf16*)&raw;
      alignas(16) bf16 ov[8];
#pragma unroll
      for (int e = 0; e < 8; ++e) ov[e] = f2b((b2f(rp[e]) + rwb[n * 64 + kk * 32 + lg * 8 + e]) * SCALE);
      qf[kk] = *(const bf16x8*)ov;
    }
#pragma unroll
    for (int ao = 0; ao < 2; ++ao) {
      int row = q0 + ao + w * 16 + lr; if (row > 2047) row = 2047;
      int4 raw = *(const int4*)&wh[((size_t)row * 4 + b) * 3072 + n * 64 + kk * 32 + lg * 8];
      const bf16* rp = (const bf16*)&raw;
      alignas(16) bf16 ov[8];
#pragma unroll
      for (int e = 0; e < 8; ++e) ov[e] = f2b((b2f(rp[e]) + rrb[n * 64 + kk * 32 + lg * 8 + e]) * SCALE);
      qrf[ao][kk] = *(const bf16x8*)ov;
    }
  }

  // --- panel GEMM: 64 cols at coordinate base pbase; sub=0 (W1: c=coord) or sub=2 (W2: c=coord-2, rows +1)
  auto panel = [&](int pbase, int sub) {
    const int aidx = sub ? 1 : 0;
#pragma unroll
    for (int nt = 0; nt < 4; ++nt) {
      int c = pbase + nt * 16 + lr - sub;
      c = c < 0 ? 0 : (c > 2047 ? 2047 : c);
      f32x4 pacc = {};
#pragma unroll
      for (int kk = 0; kk < 2; ++kk) {
        bf16x8 bfrag = *(const bf16x8*)&rk[(size_t)c * 1024 + n * 64 + kk * 32 + lg * 8];
        pacc = __builtin_amdgcn_mfma_f32_16x16x32_bf16(qrf[aidx][kk], bfrag, pacc, 0, 0, 0);
      }
      int cm = (pbase + nt * 16 + lr) & 127;
#pragma unroll
      for (int r = 0; r < 4; ++r) Tp[w * 16 + lg * 4 + r][cm] = f2b(pacc[r]);
    }
  };

  // prologue: W1 panel [1984-q0, 2048-q0)
  panel(1984 - q0, 0);

  float mrow[4] = {-1e30f, -1e30f, -1e30f, -1e30f};
  float lrow[4] = {0.f, 0.f, 0.f, 0.f};
  f32x4 oacc[4] = {};

  for (int j0 = 0; j0 < 2048; j0 += 64) {
    const int t = j0 - q0;
    __syncthreads();
#pragma unroll
    for (int i = 0; i < 2; ++i) {
      int c = tid + i * 256;
      int row = c >> 3, seg = c & 7;
      *(int4*)&Ks[row][seg * 8] = *(const int4*)&wh[((size_t)(j0 + row) * 4 + b) * 3072 + 1024 + n * 64 + seg * 8];
      int4 vv = *(const int4*)&wh[((size_t)(j0 + row) * 4 + b) * 3072 + 2048 + n * 64 + seg * 8];
      const bf16* vp = (const bf16*)&vv;
#pragma unroll
      for (int e = 0; e < 8; ++e) Vt[seg * 8 + e][row] = vp[e];
    }
    __syncthreads();

    // new BD panel for this block (per-wave rows only -> no barrier needed)
    if (t <= -64) panel(t + 2048, 0);
    else          panel(t, 2);

    // AC
    f32x4 s[4] = {};
#pragma unroll
    for (int kk = 0; kk < 2; ++kk)
#pragma unroll
      for (int f = 0; f < 4; ++f) {
        bf16x8 kf = *(const bf16x8*)&Ks[f * 16 + lr][kk * 32 + lg * 8];
        s[f] = __builtin_amdgcn_mfma_f32_16x16x32_bf16(qf[kk], kf, s[f], 0, 0, 0);
      }
    // + BD via sheared panel read
#pragma unroll
    for (int f = 0; f < 4; ++f)
#pragma unroll
      for (int r = 0; r < 4; ++r) {
        int i = q0 + w * 16 + lg * 4 + r;
        int j = j0 + f * 16 + lr;
        int u = j - i;
        float bd = 0.f;
        if (u != 1) {
          int cm = (u >= 2 ? u : u + 2047) & 127;
          bd = b2f(Tp[w * 16 + lg * 4 + r][cm]);
        }
        s[f][r] += bd;
      }
    // online softmax (rows live in 16-lane groups: reduce over xor 1,2,4,8)
    float al[4];
#pragma unroll
    for (int r = 0; r < 4; ++r) {
      float mx = fmaxf(fmaxf(s[0][r], s[1][r]), fmaxf(s[2][r], s[3][r]));
#pragma unroll
      for (int msk = 1; msk <= 8; msk <<= 1) mx = fmaxf(mx, __shfl_xor(mx, msk));
      float mnew = fmaxf(mrow[r], mx);
      al[r] = __expf(mrow[r] - mnew);
      float rs = 0.f;
#pragma unroll
      for (int f = 0; f < 4; ++f) { float p = __expf(s[f][r] - mnew); s[f][r] = p; rs += p; }
#pragma unroll
      for (int msk = 1; msk <= 8; msk <<= 1) rs += __shfl_xor(rs, msk);
      lrow[r] = lrow[r] * al[r] + rs;
      mrow[r] = mnew;
    }
#pragma unroll
    for (int f = 0; f < 4; ++f)
#pragma unroll
      for (int r = 0; r < 4; ++r) Ps[w * 16 + lg * 4 + r][f * 16 + lr] = f2b(s[f][r]);
#pragma unroll
    for (int df = 0; df < 4; ++df) {
      oacc[df][0] *= al[0]; oacc[df][1] *= al[1]; oacc[df][2] *= al[2]; oacc[df][3] *= al[3];
    }
#pragma unroll
    for (int kk = 0; kk < 2; ++kk) {
      bf16x8 pf = *(const bf16x8*)&Ps[w * 16 + lr][kk * 32 + lg * 8];
#pragma unroll
      for (int df = 0; df < 4; ++df) {
        bf16x8 vf = *(const bf16x8*)&Vt[df * 16 + lr][kk * 32 + lg * 8];
        oacc[df] = __builtin_amdgcn_mfma_f32_16x16x32_bf16(pf, vf, oacc[df], 0, 0, 0);
      }
    }
  }
#pragma unroll
  for (int df = 0; df < 4; ++df)
#pragma unroll
    for (int r = 0; r < 4; ++r) {
      int i = q0 + w * 16 + lg * 4 + r;
      av[((size_t)i * 4 + b) * 1024 + n * 64 + df * 16 + lr] = f2b(oacc[df][r] / lrow[r]);
    }
}

// ---------------- residual + LayerNorm ----------------
__global__ __launch_bounds__(256) void ln_kernel(const float* __restrict__ w, const float* __restrict__ ao,
                                                 const float* __restrict__ g, const float* __restrict__ bb,
                                                 float* __restrict__ out) {
  const int row = blockIdx.x;
  const int t = threadIdx.x;
  const float4 wv = ((const float4*)(w + (size_t)row * 1024))[t];
  const float4 av = ((const float4*)(ao + (size_t)row * 1024))[t];
  float x0 = wv.x + av.x, x1 = wv.y + av.y, x2 = wv.z + av.z, x3 = wv.w + av.w;
  float s1 = x0 + x1 + x2 + x3;
  float s2 = x0 * x0 + x1 * x1 + x2 * x2 + x3 * x3;
#pragma unroll
  for (int m = 1; m <= 32; m <<= 1) { s1 += __shfl_xor(s1, m); s2 += __shfl_xor(s2, m); }
  __shared__ float red[8];
  const int lane = t & 63, wv2 = t >> 6;
  if (lane == 0) { red[wv2] = s1; red[4 + wv2] = s2; }
  __syncthreads();
  s1 = red[0] + red[1] + red[2] + red[3];
  s2 = red[4] + red[5] + red[6] + red[7];
  const float mu = s1 * (1.f / 1024.f);
  const float var = s2 * (1.f / 1024.f) - mu * mu;
  const float rr = rsqrtf(var + 1e-5f);
  const float4 gv = ((const float4*)g)[t];
  const float4 bv = ((const float4*)bb)[t];
  float4 o;
  o.x = (x0 - mu) * rr * gv.x + bv.x;
  o.y = (x1 - mu) * rr * gv.y + bv.y;
  o.z = (x2 - mu) * rr * gv.z + bv.z;
  o.w = (x3 - mu) * rr * gv.w + bv.w;
  ((float4*)(out + (size_t)row * 1024))[t] = o;
}

extern "C" void kernel_launch(void* const* d_in, const int* in_sizes, int n_in,
                              void* d_out, int out_size, void* d_ws, size_t ws_size,
                              hipStream_t stream) {
  const float* w    = (const float*)d_in[0];
  const float* r    = (const float*)d_in[1];
  const float* qkvw = (const float*)d_in[2];
  const float* rnw  = (const float*)d_in[3];
  const float* ow   = (const float*)d_in[4];
  const float* rwb  = (const float*)d_in[5];
  const float* rrb  = (const float*)d_in[6];
  const float* lng  = (const float*)d_in[7];
  const float* lnb  = (const float*)d_in[8];
  float* out = (float*)d_out;

  char* ws = (char*)d_ws;
  size_t off = 0;
  auto alloc = [&](size_t bytes) -> char* {
    char* p = ws + off; off += (bytes + 255) & ~((size_t)255); return p;
  };
  bf16*  wb  = (bf16*)alloc((size_t)8192 * 1024 * 2);
  bf16*  qb  = (bf16*)alloc((size_t)3072 * 1024 * 2);
  bf16*  rb  = (bf16*)alloc((size_t)2048 * 1024 * 2);
  bf16*  rnb = (bf16*)alloc((size_t)1024 * 1024 * 2);
  bf16*  owb = (bf16*)alloc((size_t)1024 * 1024 * 2);
  bf16*  wh  = (bf16*)alloc((size_t)8192 * 3072 * 2);
  bf16*  rkb = (bf16*)alloc((size_t)2048 * 1024 * 2);
  bf16*  avb = (bf16*)alloc((size_t)8192 * 1024 * 2);
  float* ao  = (float*)alloc((size_t)8192 * 1024 * 4);

  auto cvt = [&](const float* in, bf16* o, size_t nelem) {
    int n4 = (int)(nelem / 4);
    cvt_kernel<<<dim3((n4 + 255) / 256), dim3(256), 0, stream>>>(in, o, n4);
  };
  cvt(w, wb, (size_t)8192 * 1024);
  cvt(qkvw, qb, (size_t)3072 * 1024);
  cvt(r, rb, (size_t)2048 * 1024);
  cvt(rnw, rnb, (size_t)1024 * 1024);
  cvt(ow, owb, (size_t)1024 * 1024);

  gemm_bt<1><<<dim3(3072 / 128, 8192 / 128), dim3(256), 0, stream>>>(wb, qb, wh, 8192, 3072, 1024);
  gemm_bt<1><<<dim3(1024 / 128, 2048 / 128), dim3(256), 0, stream>>>(rb, rnb, rkb, 2048, 1024, 1024);

  flash_kernel<<<dim3(32, 64), dim3(256), 0, stream>>>(wh, rkb, rwb, rrb, avb);

  gemm_bt<0><<<dim3(1024 / 128, 8192 / 128), dim3(256), 0, stream>>>(avb, owb, ao, 8192, 1024, 1024);
  ln_kernel<<<dim3(8192), dim3(256), 0, stream>>>(w, ao, lng, lnb, out);
}